// Round 6
// baseline (175.460 us; speedup 1.0000x reference)
//
#include <hip/hip_runtime.h>

// B = 4_194_304 rows. Per row: inputs[3] f32, targets[3] i32, cycle_state i32.
// out = mean_B( sw * (0.5*(d0+d1) + d2) ) + sum_B( range_penalty )
//
// R6: persistent software-pipelined kernel. 1024 blocks x 256 thr x 4 iters,
// register double-buffer: prefetch quad j+1's 7x16B loads, then compute quad j
// (compiler waits vmcnt(7), next loads stay in flight). Tests whether R4/R5's
// ~32us is a read-convoy artifact (one load burst per wave lifetime).

#define NTHREADS 256
#define ITERS 4                    // quads per thread, pipelined

// 2^-22 : exact power-of-two scaling for the mean over B
#define INV_B 2.384185791015625e-07f

typedef float f32x4 __attribute__((ext_vector_type(4)));
typedef int   i32x4 __attribute__((ext_vector_type(4)));

struct Quad {
    f32x4 a, b, c;      // 12 input floats (4 rows)
    i32x4 ta, tb, tc;   // 12 target ints
    i32x4 s;            // 4 cycle states
};

__device__ __forceinline__ void load_quad(Quad& Q,
    const f32x4* __restrict__ in4, const i32x4* __restrict__ tg4,
    const i32x4* __restrict__ st4, int q)
{
    Q.a  = in4[3 * q + 0];
    Q.b  = in4[3 * q + 1];
    Q.c  = in4[3 * q + 2];
    Q.ta = tg4[3 * q + 0];
    Q.tb = tg4[3 * q + 1];
    Q.tc = tg4[3 * q + 2];
    Q.s  = st4[q];
}

__device__ __forceinline__ float compute_quad(const Quad& Q, const float* w)
{
    float fin[12] = {Q.a[0], Q.a[1], Q.a[2], Q.a[3],
                     Q.b[0], Q.b[1], Q.b[2], Q.b[3],
                     Q.c[0], Q.c[1], Q.c[2], Q.c[3]};
    int   tgt[12] = {Q.ta[0], Q.ta[1], Q.ta[2], Q.ta[3],
                     Q.tb[0], Q.tb[1], Q.tb[2], Q.tb[3],
                     Q.tc[0], Q.tc[1], Q.tc[2], Q.tc[3]};
    int    st[4]  = {Q.s[0], Q.s[1], Q.s[2], Q.s[3]};

    float acc = 0.0f;
    #pragma unroll
    for (int r = 0; r < 4; ++r) {
        const float i0 = fin[3 * r + 0];
        const float i1 = fin[3 * r + 1];
        const float i2 = fin[3 * r + 2];
        const int  t2i = tgt[3 * r + 2];
        const float t0 = (float)tgt[3 * r + 0];   // exact: < 2^24
        const float t1 = (float)tgt[3 * r + 1];
        const float t2 = (float)t2i;

        const float sw = w[t2i / 100 - 1];        // t2i in {100..700}

        const float d0 = (i0 - t0) * (i0 - t0);
        const float d1 = (i1 - t1) * (i1 - t1);
        const float d2 = (i2 - t2) * (i2 - t2);
        const float mse = sw * (0.5f * (d0 + d1) + d2);

        // range tables (idx = state-1, in [0,21))
        const int idx = st[r] - 1;
        const float lo02 = (idx == 3) ? 6400.0f
                         : ((idx >= 4 && idx <= 7) ? 6000.0f : 11500.0f);
        const float hi02 = 12000.0f;
        const float lo03 = 2200.0f;
        const float hi03 = (idx == 7) ? 13000.0f : 2500.0f;

        float p = 0.0f;
        {
            const float dl = t0 - lo02, dh = t0 - hi02;
            p += (t0 < lo02) ? dl * dl : 0.0f;
            p += (t0 > hi02) ? dh * dh : 0.0f;
        }
        {
            const float dl = t1 - lo03, dh = t1 - hi03;
            p += (t1 < lo03) ? dl * dl : 0.0f;
            p += (t1 > hi03) ? dh * dh : 0.0f;
        }

        acc += mse * INV_B + p;
    }
    return acc;
}

__global__ __launch_bounds__(NTHREADS) void wmse_main(
    const f32x4* __restrict__ in4,      // [B*3/4] view of inputs
    const i32x4* __restrict__ tg4,      // [B*3/4] view of targets
    const i32x4* __restrict__ st4,      // [B/4]   view of states
    const float* __restrict__ weights,  // [7]
    float*       __restrict__ out)      // [1], pre-zeroed
{
    __shared__ float w[8];
    if (threadIdx.x < 7) w[threadIdx.x] = weights[threadIdx.x];
    __syncthreads();

    const int base = blockIdx.x * (NTHREADS * ITERS) + threadIdx.x;

    Quad buf[2];
    load_quad(buf[0], in4, tg4, st4, base);     // prologue: prefetch iter 0

    float acc = 0.0f;
    #pragma unroll
    for (int j = 0; j < ITERS; ++j) {
        if (j + 1 < ITERS)
            load_quad(buf[(j + 1) & 1], in4, tg4, st4, base + (j + 1) * NTHREADS);
        // keep the prefetch issued BEFORE the compute below (no sinking);
        // compute waits only on its own 7 loads (vmcnt(7)).
        __builtin_amdgcn_sched_barrier(0);
        acc += compute_quad(buf[j & 1], w);
    }

    // wave-64 shuffle reduce (float)
    #pragma unroll
    for (int o = 32; o > 0; o >>= 1) acc += __shfl_down(acc, o, 64);
    __shared__ float sacc[NTHREADS / 64];
    const int lane = threadIdx.x & 63;
    const int wave = threadIdx.x >> 6;
    if (lane == 0) sacc[wave] = acc;
    __syncthreads();
    if (threadIdx.x == 0) {
        float ssum = 0.0f;
        #pragma unroll
        for (int wv = 0; wv < NTHREADS / 64; ++wv) ssum += sacc[wv];
        atomicAdd(out, ssum);   // device-scope by default on global
    }
}

extern "C" void kernel_launch(void* const* d_in, const int* in_sizes, int n_in,
                              void* d_out, int out_size, void* d_ws, size_t ws_size,
                              hipStream_t stream) {
    const float* inputs  = (const float*)d_in[0];   // [B,3] f32
    const int*   targets = (const int*)  d_in[1];   // [B,3] i32
    const int*   states  = (const int*)  d_in[2];   // [B]   i32
    const float* weights = (const float*)d_in[3];   // [7]   f32

    const int B = in_sizes[2];            // cycle_states is [B]
    const int nquads = B / 4;             // 2^20 quads
    const int nblocks = nquads / (NTHREADS * ITERS);  // 1024, exact

    float* out = (float*)d_out;

    // zero the fp32 accumulator (harness poisons d_out to 0xAA before each call)
    hipMemsetAsync(out, 0, sizeof(float), stream);

    wmse_main<<<nblocks, NTHREADS, 0, stream>>>(
        (const f32x4*)inputs, (const i32x4*)targets, (const i32x4*)states,
        weights, out);
}